// Round 1
// baseline (1903.995 us; speedup 1.0000x reference)
//
#include <hip/hip_runtime.h>
#include <math.h>

#define N_NODES 10000
#define N_EDGES 300000
#define HID 128
#define F96 96
#define DIN 441
#define HPAD 448
#define TE 16

// ws float offsets
#define VLOCAL_OFF 0
#define WF_OFF     960000
#define BEFF_OFF   (WF_OFF + HID*HID)
#define BNSUM_OFF  (BEFF_OFF + HID)
#define SCSH_OFF   (BNSUM_OFF + 2*HID)
#define Y1_OFF     (SCSH_OFF + 2*HID)   // 977024, 16B aligned

// ---------------- V_local = h_V @ W_va + b_va ----------------
__global__ __launch_bounds__(HID) void k_vlocal(
        const float* __restrict__ hV, const float* __restrict__ Wva,
        const float* __restrict__ bva, float* __restrict__ Vloc) {
    __shared__ float row[HID];
    const int n = blockIdx.x;
    const int f = threadIdx.x;
    row[f] = hV[(size_t)n * HID + f];
    __syncthreads();
    if (f < F96) {
        float acc = bva[f];
        #pragma unroll 16
        for (int k = 0; k < HID; ++k) acc = fmaf(row[k], Wva[k * F96 + f], acc);
        Vloc[(size_t)n * F96 + f] = acc;
    }
}

// ---------------- Wf = W3 @ Wm_bot ; beff = b3 @ Wm_bot + bm ----------------
__global__ __launch_bounds__(HID) void k_fusew(
        const float* __restrict__ W3, const float* __restrict__ Wm,
        const float* __restrict__ b3, const float* __restrict__ bm,
        float* __restrict__ Wf, float* __restrict__ beff) {
    const int j = threadIdx.x;
    const int i = blockIdx.x;
    if (i < HID) {
        float acc = 0.0f;
        #pragma unroll 8
        for (int k = 0; k < HID; ++k)
            acc = fmaf(W3[i * HID + k], Wm[(HID + k) * HID + j], acc);
        Wf[i * HID + j] = acc;
    } else {
        float acc = bm[j];
        #pragma unroll 8
        for (int k = 0; k < HID; ++k)
            acc = fmaf(b3[k], Wm[(HID + k) * HID + j], acc);
        beff[j] = acc;
    }
}

// ---------------- fused edge kernel: features + Y1 = H @ W1 + b1 ----------------
__global__ __launch_bounds__(256) void k_edge(
        const float* __restrict__ hE, const float* __restrict__ rot,
        const float* __restrict__ trn, const int* __restrict__ eidx,
        const float* __restrict__ Wvd, const float* __restrict__ bvd,
        const float* __restrict__ W1, const float* __restrict__ b1,
        const float* __restrict__ Vloc, float* __restrict__ Y1) {
    __shared__ float sh_hE[TE][HID];   // 8 KB
    __shared__ float sh_H[TE][HPAD];   // 28.7 KB
    __shared__ float sh_Vd[TE][F96];   // 6 KB
    __shared__ float sh_R[TE][9];
    __shared__ float sh_t[TE][4];

    const int tid = threadIdx.x;
    const int e0 = blockIdx.x * TE;

    // stage h_E tile
    for (int i = tid; i < TE * HID; i += 256) {
        sh_hE[i >> 7][i & 127] = hE[(size_t)(e0 + (i >> 7)) * HID + (i & 127)];
    }
    __syncthreads();

    if (tid < 192) {
        // V_edge = h_E @ W_vd + b_vd  ->  H[0..95]
        const int f = tid % F96;
        const int eg = tid / F96;
        float acc[8];
        #pragma unroll
        for (int i = 0; i < 8; ++i) acc[i] = bvd[f];
        for (int k = 0; k < HID; k += 4) {
            const float w0 = Wvd[(k + 0) * F96 + f];
            const float w1 = Wvd[(k + 1) * F96 + f];
            const float w2 = Wvd[(k + 2) * F96 + f];
            const float w3 = Wvd[(k + 3) * F96 + f];
            #pragma unroll
            for (int i = 0; i < 8; ++i) {
                const float4 h4 = *(const float4*)&sh_hE[eg * 8 + i][k];
                acc[i] = fmaf(h4.x, w0, acc[i]);
                acc[i] = fmaf(h4.y, w1, acc[i]);
                acc[i] = fmaf(h4.z, w2, acc[i]);
                acc[i] = fmaf(h4.w, w3, acc[i]);
            }
        }
        #pragma unroll
        for (int i = 0; i < 8; ++i) sh_H[eg * 8 + i][f] = acc[i];
    } else {
        // gathers + R + t  (wave 3)
        const int t = tid - 192;
        const int e = t >> 2, q = t & 3;
        const int ge = e0 + e;
        const int s = eidx[ge];
        const int d = eidx[N_EDGES + ge];
        for (int f4 = q * 6; f4 < q * 6 + 6; ++f4) {
            const float4 vs4 = *(const float4*)&Vloc[(size_t)s * F96 + f4 * 4];
            *(float4*)&sh_H[e][F96 + f4 * 4] = vs4;    // Vs -> H[96..191]
            const float4 vd4 = *(const float4*)&Vloc[(size_t)d * F96 + f4 * 4];
            *(float4*)&sh_Vd[e][f4 * 4] = vd4;
        }
        if (q == 0) {
            #pragma unroll
            for (int i = 0; i < 9; ++i) {
                const float r = rot[(size_t)ge * 9 + i];
                sh_R[e][i] = r;
                sh_H[e][384 + i] = r;                  // quat_st
            }
            const float t0 = trn[(size_t)ge * 3 + 0];
            const float t1 = trn[(size_t)ge * 3 + 1];
            const float t2 = trn[(size_t)ge * 3 + 2];
            sh_t[e][0] = t0; sh_t[e][1] = t1; sh_t[e][2] = t2;
            sh_t[e][3] = sqrtf(t0 * t0 + t1 * t1 + t2 * t2);
        }
    }
    __syncthreads();

    // Qt[n][i] = R[i][:] . Ks[n][:] + t[i]  -> H[192..383]
    for (int u = tid; u < TE * 192; u += 256) {
        const int e = u / 192, r = u % 192;
        const int n = r / 3, i = r % 3;
        float q = sh_t[e][i];
        #pragma unroll
        for (int j = 0; j < 3; ++j)
            q = fmaf(sh_R[e][3 * i + j], sh_H[e][n * 3 + j], q);
        sh_H[e][192 + r] = q;
    }
    // QRK[n] = Vd[n] . (R @ Vs[n])  -> H[409..440]
    for (int u = tid; u < TE * 32; u += 256) {
        const int e = u >> 5, n = u & 31;
        float acc = 0.0f;
        #pragma unroll
        for (int i = 0; i < 3; ++i) {
            float rk = 0.0f;
            #pragma unroll
            for (int j = 0; j < 3; ++j)
                rk = fmaf(sh_R[e][3 * i + j], sh_H[e][F96 + n * 3 + j], rk);
            acc = fmaf(sh_Vd[e][n * 3 + i], rk, acc);
        }
        sh_H[e][409 + n] = acc;
    }
    // RBF(||t||) -> H[393..408]
    for (int u = tid; u < TE * 16; u += 256) {
        const int e = u >> 4, b = u & 15;
        const float c = (50.0f / 15.0f) * (float)b;
        const float z = (sh_t[e][3] - c) * (16.0f / 50.0f);
        sh_H[e][393 + b] = expf(-z * z);
    }
    __syncthreads();

    // Y1 = H @ W1 + b1
    const int tx = tid & 127, ty = tid >> 7;
    float acc[8];
    #pragma unroll
    for (int i = 0; i < 8; ++i) acc[i] = b1[tx];
    for (int k = 0; k < 440; k += 4) {
        const float w0 = W1[(k + 0) * HID + tx];
        const float w1 = W1[(k + 1) * HID + tx];
        const float w2 = W1[(k + 2) * HID + tx];
        const float w3 = W1[(k + 3) * HID + tx];
        #pragma unroll
        for (int i = 0; i < 8; ++i) {
            const float4 h4 = *(const float4*)&sh_H[ty * 8 + i][k];
            acc[i] = fmaf(h4.x, w0, acc[i]);
            acc[i] = fmaf(h4.y, w1, acc[i]);
            acc[i] = fmaf(h4.z, w2, acc[i]);
            acc[i] = fmaf(h4.w, w3, acc[i]);
        }
    }
    {
        const float w0 = W1[440 * HID + tx];
        #pragma unroll
        for (int i = 0; i < 8; ++i)
            acc[i] = fmaf(sh_H[ty * 8 + i][440], w0, acc[i]);
    }
    #pragma unroll
    for (int i = 0; i < 8; ++i)
        Y1[(size_t)(e0 + ty * 8 + i) * HID + tx] = acc[i];
}

// ---------------- column sums / sumsq (BN stats) ----------------
__global__ __launch_bounds__(256) void k_colstats(
        const float* __restrict__ Y, int rows_per_block, float* __restrict__ sums) {
    const int tid = threadIdx.x;
    const int f = tid & 127, half = tid >> 7;
    const int r0 = blockIdx.x * rows_per_block;
    int r1 = r0 + rows_per_block;
    if (r1 > N_EDGES) r1 = N_EDGES;
    float s = 0.0f, q = 0.0f;
    for (int e = r0 + half; e < r1; e += 2) {
        const float v = Y[(size_t)e * HID + f];
        s += v;
        q = fmaf(v, v, q);
    }
    __shared__ float sh[2][2][HID];
    sh[half][0][f] = s;
    sh[half][1][f] = q;
    __syncthreads();
    if (half == 0) {
        atomicAdd(&sums[f], s + sh[1][0][f]);
        atomicAdd(&sums[HID + f], q + sh[1][1][f]);
    }
}

// ---------------- finalize BN: scale/shift ----------------
__global__ __launch_bounds__(HID) void k_bnfin(
        const float* __restrict__ sums, const float* __restrict__ g,
        const float* __restrict__ be, float* __restrict__ scsh) {
    const int f = threadIdx.x;
    const float mean = sums[f] * (1.0f / N_EDGES);
    const float var = sums[HID + f] * (1.0f / N_EDGES) - mean * mean;
    const float sc = g[f] / sqrtf(var + 1e-5f);
    scsh[f] = sc;
    scsh[HID + f] = be[f] - mean * sc;
}

// ---------------- Y2 = relu(bn1(Y1)) @ W2 + b2 ----------------
__global__ __launch_bounds__(256) void k_layer2(
        const float* __restrict__ Y1, const float* __restrict__ W2,
        const float* __restrict__ b2, const float* __restrict__ scsh,
        float* __restrict__ Y2) {
    __shared__ float sx[TE][HID];
    const int tid = threadIdx.x;
    const int e0 = blockIdx.x * TE;
    for (int i = tid; i < TE * HID; i += 256) {
        const int k = i & 127;
        float v = Y1[(size_t)(e0 + (i >> 7)) * HID + k];
        v = fmaf(v, scsh[k], scsh[HID + k]);
        sx[i >> 7][k] = fmaxf(v, 0.0f);
    }
    __syncthreads();
    const int tx = tid & 127, ty = tid >> 7;
    float acc[8];
    #pragma unroll
    for (int i = 0; i < 8; ++i) acc[i] = b2[tx];
    for (int k = 0; k < HID; k += 4) {
        const float w0 = W2[(k + 0) * HID + tx];
        const float w1 = W2[(k + 1) * HID + tx];
        const float w2 = W2[(k + 2) * HID + tx];
        const float w3 = W2[(k + 3) * HID + tx];
        #pragma unroll
        for (int i = 0; i < 8; ++i) {
            const float4 h4 = *(const float4*)&sx[ty * 8 + i][k];
            acc[i] = fmaf(h4.x, w0, acc[i]);
            acc[i] = fmaf(h4.y, w1, acc[i]);
            acc[i] = fmaf(h4.z, w2, acc[i]);
            acc[i] = fmaf(h4.w, w3, acc[i]);
        }
    }
    #pragma unroll
    for (int i = 0; i < 8; ++i)
        Y2[(size_t)(e0 + ty * 8 + i) * HID + tx] = acc[i];
}

// ---------------- out = h_E @ Wm_top + relu(bn2(Y2)) @ Wf + beff (in-place) ----------------
__global__ __launch_bounds__(256) void k_final(
        float* __restrict__ Y2out, const float* __restrict__ hE,
        const float* __restrict__ Wm, const float* __restrict__ Wf,
        const float* __restrict__ beff, const float* __restrict__ scsh) {
    __shared__ float sx[TE][HID];
    __shared__ float se[TE][HID];
    const int tid = threadIdx.x;
    const int e0 = blockIdx.x * TE;
    for (int i = tid; i < TE * HID; i += 256) {
        const int e = i >> 7, k = i & 127;
        const size_t g = (size_t)(e0 + e) * HID + k;
        float v = Y2out[g];
        v = fmaf(v, scsh[k], scsh[HID + k]);
        sx[e][k] = fmaxf(v, 0.0f);
        se[e][k] = hE[g];
    }
    __syncthreads();
    const int tx = tid & 127, ty = tid >> 7;
    float acc[8];
    #pragma unroll
    for (int i = 0; i < 8; ++i) acc[i] = beff[tx];
    for (int k = 0; k < HID; k += 4) {
        const float w0 = Wm[(k + 0) * HID + tx];
        const float w1 = Wm[(k + 1) * HID + tx];
        const float w2 = Wm[(k + 2) * HID + tx];
        const float w3 = Wm[(k + 3) * HID + tx];
        #pragma unroll
        for (int i = 0; i < 8; ++i) {
            const float4 h4 = *(const float4*)&se[ty * 8 + i][k];
            acc[i] = fmaf(h4.x, w0, acc[i]);
            acc[i] = fmaf(h4.y, w1, acc[i]);
            acc[i] = fmaf(h4.z, w2, acc[i]);
            acc[i] = fmaf(h4.w, w3, acc[i]);
        }
    }
    for (int k = 0; k < HID; k += 4) {
        const float w0 = Wf[(k + 0) * HID + tx];
        const float w1 = Wf[(k + 1) * HID + tx];
        const float w2 = Wf[(k + 2) * HID + tx];
        const float w3 = Wf[(k + 3) * HID + tx];
        #pragma unroll
        for (int i = 0; i < 8; ++i) {
            const float4 h4 = *(const float4*)&sx[ty * 8 + i][k];
            acc[i] = fmaf(h4.x, w0, acc[i]);
            acc[i] = fmaf(h4.y, w1, acc[i]);
            acc[i] = fmaf(h4.z, w2, acc[i]);
            acc[i] = fmaf(h4.w, w3, acc[i]);
        }
    }
    #pragma unroll
    for (int i = 0; i < 8; ++i)
        Y2out[(size_t)(e0 + ty * 8 + i) * HID + tx] = acc[i];
}

extern "C" void kernel_launch(void* const* d_in, const int* in_sizes, int n_in,
                              void* d_out, int out_size, void* d_ws, size_t ws_size,
                              hipStream_t stream) {
    (void)in_sizes; (void)n_in; (void)out_size; (void)ws_size;
    const float* hV   = (const float*)d_in[0];
    const float* hE   = (const float*)d_in[1];
    const float* rot  = (const float*)d_in[2];
    const float* trn  = (const float*)d_in[3];
    const int*   eidx = (const int*)  d_in[4];
    const float* Wva  = (const float*)d_in[5];
    const float* bva  = (const float*)d_in[6];
    const float* Wvd  = (const float*)d_in[7];
    const float* bvd  = (const float*)d_in[8];
    const float* W1   = (const float*)d_in[9];
    const float* b1   = (const float*)d_in[10];
    const float* g1   = (const float*)d_in[11];
    const float* be1  = (const float*)d_in[12];
    const float* W2   = (const float*)d_in[13];
    const float* b2   = (const float*)d_in[14];
    const float* g2   = (const float*)d_in[15];
    const float* be2  = (const float*)d_in[16];
    const float* W3   = (const float*)d_in[17];
    const float* b3   = (const float*)d_in[18];
    const float* Wm   = (const float*)d_in[19];
    const float* bm   = (const float*)d_in[20];

    float* out  = (float*)d_out;
    float* ws   = (float*)d_ws;
    float* Vloc = ws + VLOCAL_OFF;
    float* Wf   = ws + WF_OFF;
    float* beff = ws + BEFF_OFF;
    float* bns  = ws + BNSUM_OFF;
    float* scsh = ws + SCSH_OFF;
    float* Y1   = ws + Y1_OFF;

    k_vlocal<<<N_NODES, HID, 0, stream>>>(hV, Wva, bva, Vloc);
    k_fusew<<<HID + 1, HID, 0, stream>>>(W3, Wm, b3, bm, Wf, beff);
    k_edge<<<N_EDGES / TE, 256, 0, stream>>>(hE, rot, trn, eidx, Wvd, bvd, W1, b1, Vloc, Y1);

    hipMemsetAsync(bns, 0, 2 * HID * sizeof(float), stream);
    k_colstats<<<1024, 256, 0, stream>>>(Y1, (N_EDGES + 1023) / 1024, bns);
    k_bnfin<<<1, HID, 0, stream>>>(bns, g1, be1, scsh);
    k_layer2<<<N_EDGES / TE, 256, 0, stream>>>(Y1, W2, b2, scsh, out);

    hipMemsetAsync(bns, 0, 2 * HID * sizeof(float), stream);
    k_colstats<<<1024, 256, 0, stream>>>(out, (N_EDGES + 1023) / 1024, bns);
    k_bnfin<<<1, HID, 0, stream>>>(bns, g2, be2, scsh);
    k_final<<<N_EDGES / TE, 256, 0, stream>>>(out, hE, Wm, Wf, beff, scsh);
}

// Round 3
// 872.993 us; speedup vs baseline: 2.1810x; 2.1810x over previous
//
#include <hip/hip_runtime.h>
#include <math.h>

typedef _Float16 f16;
typedef _Float16 f16x8 __attribute__((ext_vector_type(8)));
typedef _Float16 f16x4 __attribute__((ext_vector_type(4)));
typedef _Float16 f16x2 __attribute__((ext_vector_type(2)));
typedef float f32x4 __attribute__((ext_vector_type(4)));

#define N_NODES 10000
#define N_EDGES 300000
#define HID 128
#define F96 96

// ws float offsets.
// Lifetimes: Vloc dies after k_edge; Y2 is born in k_layer2 -> Y2 may overlap Vloc.
// Y1/Y2 are fp16: 300000*128 halves = 38,400,000 halves = 19,200,000 floats EACH.
#define VLOCAL_OFF 0                          // 960,000 floats (dead after k_edge)
#define Y2_OFF     0                          // 19,200,000 floats (overlaps Vloc - OK)
#define Y1_OFF     19200000                   // 19,200,000 floats
#define WF_OFF     38400000                   // +16384
#define BEFF_OFF   (WF_OFF + 16384)           // +128
#define BNSUM_OFF  (BEFF_OFF + 128)           // +256
#define SCSH_OFF   (BNSUM_OFF + 256)          // +256
#define WVDT_OFF   (SCSH_OFF + 256)           // 96*128 h   = 6144 floats
#define W1T_OFF    (WVDT_OFF + 6144)          // 128*448 h  = 28672 floats
#define W2T_OFF    (W1T_OFF + 28672)          // 128*128 h  = 8192 floats
#define BFT_OFF    (W2T_OFF + 8192)           // 128*256 h  = 16384 floats
// end = 38,476,416 floats = 153.9 MB (< 157.5 MB proven available in round 1)

__device__ __forceinline__ f32x4 mfma16(f16x8 a, f16x8 b, f32x4 c) {
    return __builtin_amdgcn_mfma_f32_16x16x32_f16(a, b, c, 0, 0, 0);
}

__device__ __forceinline__ f16x8 ldf8cvt(const float* p) {
    const float4 a = *(const float4*)p;
    const float4 b = *(const float4*)(p + 4);
    f16x8 r;
    r[0] = (f16)a.x; r[1] = (f16)a.y; r[2] = (f16)a.z; r[3] = (f16)a.w;
    r[4] = (f16)b.x; r[5] = (f16)b.y; r[6] = (f16)b.z; r[7] = (f16)b.w;
    return r;
}

// ---------------- V_local = h_V @ W_va + b_va (fp32, small) ----------------
__global__ __launch_bounds__(HID) void k_vlocal(
        const float* __restrict__ hV, const float* __restrict__ Wva,
        const float* __restrict__ bva, float* __restrict__ Vloc) {
    __shared__ float row[HID];
    const int n = blockIdx.x;
    const int f = threadIdx.x;
    row[f] = hV[(size_t)n * HID + f];
    __syncthreads();
    if (f < F96) {
        float acc = bva[f];
        #pragma unroll 16
        for (int k = 0; k < HID; ++k) acc = fmaf(row[k], Wva[k * F96 + f], acc);
        Vloc[(size_t)n * F96 + f] = acc;
    }
}

// ---------------- Wf = W3 @ Wm_bot (fp32); beff = b3 @ Wm_bot + bm ----------------
__global__ __launch_bounds__(HID) void k_fusew(
        const float* __restrict__ W3, const float* __restrict__ Wm,
        const float* __restrict__ b3, const float* __restrict__ bm,
        float* __restrict__ Wf, float* __restrict__ beff) {
    const int j = threadIdx.x;
    const int i = blockIdx.x;
    if (i < HID) {
        float acc = 0.0f;
        #pragma unroll 8
        for (int k = 0; k < HID; ++k)
            acc = fmaf(W3[i * HID + k], Wm[(HID + k) * HID + j], acc);
        Wf[i * HID + j] = acc;
    } else {
        float acc = bm[j];
        #pragma unroll 8
        for (int k = 0; k < HID; ++k)
            acc = fmaf(b3[k], Wm[(HID + k) * HID + j], acc);
        beff[j] = acc;
    }
}

// ---------------- transpose+cvt weights to fp16 B-layout BT[n][k] ----------------
__global__ __launch_bounds__(HID) void k_prep(
        const float* __restrict__ Wvd, const float* __restrict__ W1,
        const float* __restrict__ W2, const float* __restrict__ Wm,
        const float* __restrict__ Wf,
        f16* __restrict__ WvdT, f16* __restrict__ W1T,
        f16* __restrict__ W2T, f16* __restrict__ BfT) {
    const int b = blockIdx.x, t = threadIdx.x;
    if (b < 96) {                       // WvdT[96][128]
        WvdT[b * 128 + t] = (f16)Wvd[t * 96 + b];
    } else if (b < 224) {               // W1T[128][448], zero-pad k>=441
        const int n = b - 96;
        for (int k = t; k < 448; k += 128)
            W1T[n * 448 + k] = (k < 441) ? (f16)W1[k * 128 + n] : (f16)0.0f;
    } else if (b < 352) {               // W2T[128][128]
        const int n = b - 224;
        W2T[n * 128 + t] = (f16)W2[t * 128 + n];
    } else {                            // BfT[128][256] = [Wf ; Wm_top]^T
        const int n = b - 352;
        BfT[n * 256 + t]       = (f16)Wf[t * 128 + n];
        BfT[n * 256 + 128 + t] = (f16)Wm[t * 128 + n];
    }
}

// ---------------- fused edge kernel: features + Y1 = H @ W1 + b1 (MFMA) ----------------
__global__ __launch_bounds__(256) void k_edge(
        const float* __restrict__ hE, const float* __restrict__ rot,
        const float* __restrict__ trn, const int* __restrict__ eidx,
        const f16* __restrict__ WvdT, const float* __restrict__ bvd,
        const f16* __restrict__ W1T, const float* __restrict__ b1,
        const float* __restrict__ Vloc, f16* __restrict__ Y1) {
    __shared__ f16   sh_H[32][456];    // H features fp16, stride 912B (=16 mod 128: conflict-free b128)
    __shared__ float sh_Vd[32][96];    // V_local[dst] fp32; reused as f16 repack buf [32][136]
    __shared__ float sh_R[32][9];
    __shared__ float sh_t[32][4];

    const int tid = threadIdx.x;
    const int l   = tid & 63;
    const int w   = tid >> 6;
    const int l15 = l & 15;
    const int q   = l >> 4;
    const int e0  = blockIdx.x * 32;

    // ---- stage 0a: gathers + R/t (8 threads per edge) ----
    {
        const int e  = tid >> 3, s8 = tid & 7;
        const int ge = e0 + e;
        const int s  = eidx[ge];
        const int d  = eidx[N_EDGES + ge];
        #pragma unroll
        for (int f4 = s8 * 3; f4 < s8 * 3 + 3; ++f4) {
            const float4 vs = *(const float4*)&Vloc[(size_t)s * F96 + f4 * 4];
            f16x4 hv; hv[0] = (f16)vs.x; hv[1] = (f16)vs.y; hv[2] = (f16)vs.z; hv[3] = (f16)vs.w;
            *(f16x4*)&sh_H[e][F96 + f4 * 4] = hv;          // Vs -> H[96..192)
            const float4 vd = *(const float4*)&Vloc[(size_t)d * F96 + f4 * 4];
            *(float4*)&sh_Vd[e][f4 * 4] = vd;
        }
        if (s8 == 0) {
            #pragma unroll
            for (int i = 0; i < 9; ++i) {
                const float r = rot[(size_t)ge * 9 + i];
                sh_R[e][i] = r;
                sh_H[e][384 + i] = (f16)r;                 // quat_st
            }
            const float t0 = trn[(size_t)ge * 3 + 0];
            const float t1 = trn[(size_t)ge * 3 + 1];
            const float t2 = trn[(size_t)ge * 3 + 2];
            sh_t[e][0] = t0; sh_t[e][1] = t1; sh_t[e][2] = t2;
            sh_t[e][3] = sqrtf(t0 * t0 + t1 * t1 + t2 * t2);
            #pragma unroll
            for (int i = 441; i < 448; ++i) sh_H[e][i] = (f16)0.0f;  // K-pad
        }
    }

    // ---- stage 0b: V_edge = h_E @ W_vd + b_vd via MFMA -> H[0..96) ----
    {
        const int m   = w >> 1;              // m-tile (16 edges)
        const int nt0 = (w & 1) * 3;         // 3 n-tiles per wave
        f32x4 acc0 = {0.f,0.f,0.f,0.f}, acc1 = acc0, acc2 = acc0;
        const float* arow = &hE[(size_t)(e0 + m * 16 + l15) * HID + q * 8];
        const f16*   bp   = &WvdT[(nt0 * 16 + l15) * 128 + q * 8];
        #pragma unroll
        for (int kc = 0; kc < 4; ++kc) {
            const f16x8 af  = ldf8cvt(arow + kc * 32);
            const f16x8 bf0 = *(const f16x8*)(bp + kc * 32);
            const f16x8 bf1 = *(const f16x8*)(bp + 16 * 128 + kc * 32);
            const f16x8 bf2 = *(const f16x8*)(bp + 32 * 128 + kc * 32);
            acc0 = mfma16(af, bf0, acc0);
            acc1 = mfma16(af, bf1, acc1);
            acc2 = mfma16(af, bf2, acc2);
        }
        f32x4 av[3] = {acc0, acc1, acc2};
        #pragma unroll
        for (int t3 = 0; t3 < 3; ++t3) {
            const int col = (nt0 + t3) * 16 + l15;
            const float bb = bvd[col];
            #pragma unroll
            for (int r = 0; r < 4; ++r)
                sh_H[m * 16 + q * 4 + r][col] = (f16)(av[t3][r] + bb);
        }
    }
    __syncthreads();

    // ---- stage 1: Qt (+QRK via RK = Qt - t) + RBF ----
    {
        const int e  = tid >> 3;
        const int n0 = tid & 7;
        float R0 = sh_R[e][0], R1 = sh_R[e][1], R2 = sh_R[e][2];
        float R3 = sh_R[e][3], R4 = sh_R[e][4], R5 = sh_R[e][5];
        float R6 = sh_R[e][6], R7 = sh_R[e][7], R8 = sh_R[e][8];
        const float t0 = sh_t[e][0], t1 = sh_t[e][1], t2 = sh_t[e][2];
        #pragma unroll
        for (int n = n0; n < 64; n += 8) {
            const float k0 = (float)sh_H[e][n * 3 + 0];
            const float k1 = (float)sh_H[e][n * 3 + 1];
            const float k2 = (float)sh_H[e][n * 3 + 2];
            const float q0 = fmaf(R0, k0, fmaf(R1, k1, fmaf(R2, k2, t0)));
            const float q1 = fmaf(R3, k0, fmaf(R4, k1, fmaf(R5, k2, t1)));
            const float q2 = fmaf(R6, k0, fmaf(R7, k1, fmaf(R8, k2, t2)));
            sh_H[e][192 + n * 3 + 0] = (f16)q0;
            sh_H[e][192 + n * 3 + 1] = (f16)q1;
            sh_H[e][192 + n * 3 + 2] = (f16)q2;
            if (n >= 32) {                    // QRK[n-32] = Vd . (R@Vs) = Vd . (Qt - t)
                const float* vd = &sh_Vd[e][(n - 32) * 3];
                const float qrk = (q0 - t0) * vd[0] + (q1 - t1) * vd[1] + (q2 - t2) * vd[2];
                sh_H[e][409 + (n - 32)] = (f16)qrk;
            }
        }
        const float tn = sh_t[e][3];
        #pragma unroll
        for (int b = n0 * 2; b < n0 * 2 + 2; ++b) {
            const float c = (50.0f / 15.0f) * (float)b;
            const float z = (tn - c) * (16.0f / 50.0f);
            sh_H[e][393 + b] = (f16)expf(-z * z);
        }
    }
    __syncthreads();

    // ---- stage 2: Y1 = H @ W1 + b1 (MFMA, K=448) ----
    {
        const int nt0 = w * 2;
        f32x4 acc[2][2] = {};
        const f16* bp = &W1T[(nt0 * 16 + l15) * 448 + q * 8];
        #pragma unroll 2
        for (int kc = 0; kc < 14; ++kc) {
            const f16x8 a0  = *(const f16x8*)&sh_H[l15][kc * 32 + q * 8];
            const f16x8 a1  = *(const f16x8*)&sh_H[16 + l15][kc * 32 + q * 8];
            const f16x8 bb0 = *(const f16x8*)(bp + kc * 32);
            const f16x8 bb1 = *(const f16x8*)(bp + 16 * 448 + kc * 32);
            acc[0][0] = mfma16(a0, bb0, acc[0][0]);
            acc[1][0] = mfma16(a1, bb0, acc[1][0]);
            acc[0][1] = mfma16(a0, bb1, acc[0][1]);
            acc[1][1] = mfma16(a1, bb1, acc[1][1]);
        }
        f16* shY = (f16*)sh_Vd;               // [32][136] halves (8704 B <= 12288 B)
        #pragma unroll
        for (int mi = 0; mi < 2; ++mi)
            #pragma unroll
            for (int ni = 0; ni < 2; ++ni) {
                const int col = (nt0 + ni) * 16 + l15;
                const float bb = b1[col];
                #pragma unroll
                for (int r = 0; r < 4; ++r)
                    shY[(mi * 16 + q * 4 + r) * 136 + col] = (f16)(acc[mi][ni][r] + bb);
            }
    }
    __syncthreads();
    {
        const f16* shY = (const f16*)sh_Vd;
        for (int c = tid; c < 512; c += 256) {
            const int e = c >> 4, seg = c & 15;
            *(f16x8*)&Y1[(size_t)(e0 + e) * HID + seg * 8] =
                *(const f16x8*)&shY[e * 136 + seg * 8];
        }
    }
}

// ---------------- column sums / sumsq over fp16 matrix ----------------
__global__ __launch_bounds__(256) void k_colstats_h(
        const f16* __restrict__ Y, int rows_per_block, float* __restrict__ sums) {
    const int tid = threadIdx.x;
    const int c2 = tid & 63;
    const int g  = tid >> 6;
    const int r0 = blockIdx.x * rows_per_block;
    int r1 = r0 + rows_per_block;
    if (r1 > N_EDGES) r1 = N_EDGES;
    float s0 = 0.f, q0 = 0.f, s1 = 0.f, q1 = 0.f;
    for (int e = r0 + g; e < r1; e += 4) {
        const f16x2 v = *(const f16x2*)&Y[(size_t)e * HID + c2 * 2];
        const float a = (float)v[0], b = (float)v[1];
        s0 += a; q0 = fmaf(a, a, q0);
        s1 += b; q1 = fmaf(b, b, q1);
    }
    __shared__ float sh[4][2][HID];
    sh[g][0][c2 * 2] = s0; sh[g][0][c2 * 2 + 1] = s1;
    sh[g][1][c2 * 2] = q0; sh[g][1][c2 * 2 + 1] = q1;
    __syncthreads();
    if (tid < HID) {
        atomicAdd(&sums[tid], sh[0][0][tid] + sh[1][0][tid] + sh[2][0][tid] + sh[3][0][tid]);
    } else if (tid < 2 * HID) {
        const int f = tid - HID;
        atomicAdd(&sums[HID + f], sh[0][1][f] + sh[1][1][f] + sh[2][1][f] + sh[3][1][f]);
    }
}

// ---------------- finalize BN: scale/shift ----------------
__global__ __launch_bounds__(HID) void k_bnfin(
        const float* __restrict__ sums, const float* __restrict__ g,
        const float* __restrict__ be, float* __restrict__ scsh) {
    const int f = threadIdx.x;
    const float mean = sums[f] * (1.0f / N_EDGES);
    const float var  = sums[HID + f] * (1.0f / N_EDGES) - mean * mean;
    const float sc   = g[f] / sqrtf(var + 1e-5f);
    scsh[f] = sc;
    scsh[HID + f] = be[f] - mean * sc;
}

// ---------------- Y2 = relu(bn1(Y1)) @ W2 + b2 (MFMA) ----------------
__global__ __launch_bounds__(256) void k_layer2(
        const f16* __restrict__ Y1, const f16* __restrict__ W2T,
        const float* __restrict__ b2, const float* __restrict__ scsh,
        f16* __restrict__ Y2) {
    __shared__ f16 shY[32 * 136];
    const int tid = threadIdx.x;
    const int l = tid & 63, w = tid >> 6;
    const int l15 = l & 15, q = l >> 4;
    const int e0 = blockIdx.x * 32;
    const int nt0 = w * 2;
    f32x4 acc[2][2] = {};
    const f16* bp = &W2T[(nt0 * 16 + l15) * 128 + q * 8];
    #pragma unroll
    for (int kc = 0; kc < 4; ++kc) {
        const int k = kc * 32 + q * 8;
        const float4 sc0 = *(const float4*)&scsh[k];
        const float4 sc1 = *(const float4*)&scsh[k + 4];
        const float4 sf0 = *(const float4*)&scsh[HID + k];
        const float4 sf1 = *(const float4*)&scsh[HID + k + 4];
        f16x8 af[2];
        #pragma unroll
        for (int mi = 0; mi < 2; ++mi) {
            const f16x8 ah = *(const f16x8*)&Y1[(size_t)(e0 + mi * 16 + l15) * HID + k];
            f16x8 a;
            a[0] = (f16)fmaxf(fmaf((float)ah[0], sc0.x, sf0.x), 0.f);
            a[1] = (f16)fmaxf(fmaf((float)ah[1], sc0.y, sf0.y), 0.f);
            a[2] = (f16)fmaxf(fmaf((float)ah[2], sc0.z, sf0.z), 0.f);
            a[3] = (f16)fmaxf(fmaf((float)ah[3], sc0.w, sf0.w), 0.f);
            a[4] = (f16)fmaxf(fmaf((float)ah[4], sc1.x, sf1.x), 0.f);
            a[5] = (f16)fmaxf(fmaf((float)ah[5], sc1.y, sf1.y), 0.f);
            a[6] = (f16)fmaxf(fmaf((float)ah[6], sc1.z, sf1.z), 0.f);
            a[7] = (f16)fmaxf(fmaf((float)ah[7], sc1.w, sf1.w), 0.f);
            af[mi] = a;
        }
        const f16x8 b0 = *(const f16x8*)(bp + kc * 32);
        const f16x8 b1v = *(const f16x8*)(bp + 16 * 128 + kc * 32);
        acc[0][0] = mfma16(af[0], b0, acc[0][0]);
        acc[1][0] = mfma16(af[1], b0, acc[1][0]);
        acc[0][1] = mfma16(af[0], b1v, acc[0][1]);
        acc[1][1] = mfma16(af[1], b1v, acc[1][1]);
    }
    #pragma unroll
    for (int mi = 0; mi < 2; ++mi)
        #pragma unroll
        for (int ni = 0; ni < 2; ++ni) {
            const int col = (nt0 + ni) * 16 + l15;
            const float bb = b2[col];
            #pragma unroll
            for (int r = 0; r < 4; ++r)
                shY[(mi * 16 + q * 4 + r) * 136 + col] = (f16)(acc[mi][ni][r] + bb);
        }
    __syncthreads();
    for (int c = tid; c < 512; c += 256) {
        const int e = c >> 4, seg = c & 15;
        *(f16x8*)&Y2[(size_t)(e0 + e) * HID + seg * 8] =
            *(const f16x8*)&shY[e * 136 + seg * 8];
    }
}

// ---------------- out = [relu(bn2(Y2)) | h_E] @ [Wf ; Wm_top] + beff (MFMA, K=256) ----------------
__global__ __launch_bounds__(256) void k_final(
        const f16* __restrict__ Y2, const float* __restrict__ hE,
        const f16* __restrict__ BfT, const float* __restrict__ beff,
        const float* __restrict__ scsh, float* __restrict__ out) {
    __shared__ float shO[32 * 132];
    const int tid = threadIdx.x;
    const int l = tid & 63, w = tid >> 6;
    const int l15 = l & 15, q = l >> 4;
    const int e0 = blockIdx.x * 32;
    const int nt0 = w * 2;
    f32x4 acc[2][2] = {};
    const f16* bp = &BfT[(nt0 * 16 + l15) * 256 + q * 8];
    #pragma unroll
    for (int kc = 0; kc < 8; ++kc) {
        const int k = kc * 32 + q * 8;
        f16x8 af[2];
        if (kc < 4) {
            const float4 sc0 = *(const float4*)&scsh[k];
            const float4 sc1 = *(const float4*)&scsh[k + 4];
            const float4 sf0 = *(const float4*)&scsh[HID + k];
            const float4 sf1 = *(const float4*)&scsh[HID + k + 4];
            #pragma unroll
            for (int mi = 0; mi < 2; ++mi) {
                const f16x8 ah = *(const f16x8*)&Y2[(size_t)(e0 + mi * 16 + l15) * HID + k];
                f16x8 a;
                a[0] = (f16)fmaxf(fmaf((float)ah[0], sc0.x, sf0.x), 0.f);
                a[1] = (f16)fmaxf(fmaf((float)ah[1], sc0.y, sf0.y), 0.f);
                a[2] = (f16)fmaxf(fmaf((float)ah[2], sc0.z, sf0.z), 0.f);
                a[3] = (f16)fmaxf(fmaf((float)ah[3], sc0.w, sf0.w), 0.f);
                a[4] = (f16)fmaxf(fmaf((float)ah[4], sc1.x, sf1.x), 0.f);
                a[5] = (f16)fmaxf(fmaf((float)ah[5], sc1.y, sf1.y), 0.f);
                a[6] = (f16)fmaxf(fmaf((float)ah[6], sc1.z, sf1.z), 0.f);
                a[7] = (f16)fmaxf(fmaf((float)ah[7], sc1.w, sf1.w), 0.f);
                af[mi] = a;
            }
        } else {
            const int kk = k - 128;
            #pragma unroll
            for (int mi = 0; mi < 2; ++mi)
                af[mi] = ldf8cvt(&hE[(size_t)(e0 + mi * 16 + l15) * HID + kk]);
        }
        const f16x8 b0 = *(const f16x8*)(bp + kc * 32);
        const f16x8 b1v = *(const f16x8*)(bp + 16 * 256 + kc * 32);
        acc[0][0] = mfma16(af[0], b0, acc[0][0]);
        acc[1][0] = mfma16(af[1], b0, acc[1][0]);
        acc[0][1] = mfma16(af[0], b1v, acc[0][1]);
        acc[1][1] = mfma16(af[1], b1v, acc[1][1]);
    }
    #pragma unroll
    for (int mi = 0; mi < 2; ++mi)
        #pragma unroll
        for (int ni = 0; ni < 2; ++ni) {
            const int col = (nt0 + ni) * 16 + l15;
            const float bb = beff[col];
            #pragma unroll
            for (int r = 0; r < 4; ++r)
                shO[(mi * 16 + q * 4 + r) * 132 + col] = acc[mi][ni][r] + bb;
        }
    __syncthreads();
    for (int c = tid; c < 1024; c += 256) {
        const int e = c >> 5, seg = c & 31;
        *(float4*)&out[(size_t)(e0 + e) * HID + seg * 4] =
            *(const float4*)&shO[e * 132 + seg * 4];
    }
}

extern "C" void kernel_launch(void* const* d_in, const int* in_sizes, int n_in,
                              void* d_out, int out_size, void* d_ws, size_t ws_size,
                              hipStream_t stream) {
    (void)in_sizes; (void)n_in; (void)out_size; (void)ws_size;
    const float* hV   = (const float*)d_in[0];
    const float* hE   = (const float*)d_in[1];
    const float* rot  = (const float*)d_in[2];
    const float* trn  = (const float*)d_in[3];
    const int*   eidx = (const int*)  d_in[4];
    const float* Wva  = (const float*)d_in[5];
    const float* bva  = (const float*)d_in[6];
    const float* Wvd  = (const float*)d_in[7];
    const float* bvd  = (const float*)d_in[8];
    const float* W1   = (const float*)d_in[9];
    const float* b1   = (const float*)d_in[10];
    const float* g1   = (const float*)d_in[11];
    const float* be1  = (const float*)d_in[12];
    const float* W2   = (const float*)d_in[13];
    const float* b2   = (const float*)d_in[14];
    const float* g2   = (const float*)d_in[15];
    const float* be2  = (const float*)d_in[16];
    const float* W3   = (const float*)d_in[17];
    const float* b3   = (const float*)d_in[18];
    const float* Wm   = (const float*)d_in[19];
    const float* bm   = (const float*)d_in[20];

    float* out  = (float*)d_out;
    float* ws   = (float*)d_ws;
    float* Vloc = ws + VLOCAL_OFF;
    float* Wf   = ws + WF_OFF;
    float* beff = ws + BEFF_OFF;
    float* bns  = ws + BNSUM_OFF;
    float* scsh = ws + SCSH_OFF;
    f16*   Y1   = (f16*)(ws + Y1_OFF);
    f16*   Y2   = (f16*)(ws + Y2_OFF);
    f16*   WvdT = (f16*)(ws + WVDT_OFF);
    f16*   W1T  = (f16*)(ws + W1T_OFF);
    f16*   W2T  = (f16*)(ws + W2T_OFF);
    f16*   BfT  = (f16*)(ws + BFT_OFF);

    k_vlocal<<<N_NODES, HID, 0, stream>>>(hV, Wva, bva, Vloc);
    k_fusew<<<HID + 1, HID, 0, stream>>>(W3, Wm, b3, bm, Wf, beff);
    k_prep<<<480, HID, 0, stream>>>(Wvd, W1, W2, Wm, Wf, WvdT, W1T, W2T, BfT);

    k_edge<<<N_EDGES / 32, 256, 0, stream>>>(hE, rot, trn, eidx, WvdT, bvd, W1T, b1, Vloc, Y1);

    hipMemsetAsync(bns, 0, 2 * HID * sizeof(float), stream);
    k_colstats_h<<<1024, 256, 0, stream>>>(Y1, (N_EDGES + 1023) / 1024, bns);
    k_bnfin<<<1, HID, 0, stream>>>(bns, g1, be1, scsh);
    k_layer2<<<N_EDGES / 32, 256, 0, stream>>>(Y1, W2T, b2, scsh, Y2);

    hipMemsetAsync(bns, 0, 2 * HID * sizeof(float), stream);
    k_colstats_h<<<1024, 256, 0, stream>>>(Y2, (N_EDGES + 1023) / 1024, bns);
    k_bnfin<<<1, HID, 0, stream>>>(bns, g2, be2, scsh);
    k_final<<<N_EDGES / 32, 256, 0, stream>>>(Y2, hE, BfT, beff, scsh, out);
}